// Round 7
// baseline (234.943 us; speedup 1.0000x reference)
//
#include <hip/hip_runtime.h>

// Inverse 3D Haar (UnPatcher): in  [B=2, 8*G=128, T=8,  H=128, W=128] f32
//                              out [B=2,   G=16, 2T=16, 2H=256, 2W=256] f32
//
// out[b,g,2ti+pT,2hi+pH,2wi+pW] = (1/8) * sum_s (-1)^(bits(s)·(pT,pH,pW)) *
//                                 in[b, s*16+g, ti, hi, wi],  s = 4tb+2hb+wb.
//
// R4: nt stores -> 1.7x write amplification (no L2 write-combine). reverted.
// R5: ideal traffic (131MB W / 65MB F) but 86us vs 43us roofline.
// R6: lane-contiguous stores + float2 loads: 84us — store shape NOT the
//     limiter. Little's law says waves are queue-stalled with tiny per-wave
//     in-flight bytes.
// R7 (this): 4x work per thread — 2 hi x float4, 16 independent 16B loads
//     (16KiB/wave outstanding), amortize wave overhead. MLP test.

__device__ __forceinline__ float4 add4(float4 a, float4 b) {
    return make_float4(a.x + b.x, a.y + b.y, a.z + b.z, a.w + b.w);
}
__device__ __forceinline__ float4 sub4(float4 a, float4 b) {
    return make_float4(a.x - b.x, a.y - b.y, a.z - b.z, a.w - b.w);
}
__device__ __forceinline__ float4 scl4(float4 a, float s) {
    return make_float4(a.x * s, a.y * s, a.z * s, a.w * s);
}

__global__ __launch_bounds__(256) void ihaar3d_kernel(const float* __restrict__ in,
                                                      float* __restrict__ out) {
    constexpr int TI = 8, HI = 128, WI = 128;   // input spatial dims
    constexpr int G  = 16;                      // output channels per batch
    constexpr int WQ = WI / 4;                  // 32 float4 per input W-row
    constexpr int HH = HI / 2;                  // hi handled in pairs (hi, hi+64)

    int idx = blockIdx.x * blockDim.x + threadIdx.x;
    const int wq = idx & (WQ - 1); idx >>= 5;   // float4 index along W_in
    const int h0 = idx & (HH - 1); idx >>= 6;   // first hi of the pair
    const int ti = idx & (TI - 1); idx >>= 3;
    const int g  = idx & (G  - 1); idx >>= 4;
    const int b  = idx;                         // 0..1

    const long sstride = (long)16 * TI * HI * WI;  // subband stride (1 MiB/4B)
    const long chBase  = (((long)(b * 128 + g) * TI + ti) * HI) * WI;

    // ---- issue ALL 16 loads first (2 hi x 8 subbands), fully independent ----
    float4 v[2][8];
#pragma unroll
    for (int k = 0; k < 2; ++k) {
        const int hi = h0 + k * HH;
        const long inBase = chBase + (long)hi * WI + (long)wq * 4;
#pragma unroll
        for (int s = 0; s < 8; ++s)
            v[k][s] = *reinterpret_cast<const float4*>(in + inBase + (long)s * sstride);
    }

    const int TO = 2 * TI, HO = 2 * HI, WO = 2 * WI;
    const long outCh = ((long)(b * G + g) * TO + 2 * ti) * HO;  // row index base

#pragma unroll
    for (int k = 0; k < 2; ++k) {
        const int hi = h0 + k * HH;

        // ---- 3-stage butterfly, statically indexed ----
        float4 A[2][2][2];  // [tb][hb][pW]
#pragma unroll
        for (int tb = 0; tb < 2; ++tb)
#pragma unroll
            for (int hb = 0; hb < 2; ++hb) {
                const float4 lo = v[k][4 * tb + 2 * hb + 0];
                const float4 hv = v[k][4 * tb + 2 * hb + 1];
                A[tb][hb][0] = add4(lo, hv);
                A[tb][hb][1] = sub4(lo, hv);
            }
        float4 Bv[2][2][2];  // [tb][pH][pW]
#pragma unroll
        for (int tb = 0; tb < 2; ++tb)
#pragma unroll
            for (int pw = 0; pw < 2; ++pw) {
                Bv[tb][0][pw] = add4(A[tb][0][pw], A[tb][1][pw]);
                Bv[tb][1][pw] = sub4(A[tb][0][pw], A[tb][1][pw]);
            }
        float4 Cv[2][2][2];  // [pT][pH][pW], scaled by 1/8
#pragma unroll
        for (int ph = 0; ph < 2; ++ph)
#pragma unroll
            for (int pw = 0; pw < 2; ++pw) {
                Cv[0][ph][pw] = scl4(add4(Bv[0][ph][pw], Bv[1][ph][pw]), 0.125f);
                Cv[1][ph][pw] = scl4(sub4(Bv[0][ph][pw], Bv[1][ph][pw]), 0.125f);
            }

        // ---- scatter 2x2x8 output block ----
        const long outBase = (outCh + 2 * hi) * WO + (long)wq * 8;
#pragma unroll
        for (int pt = 0; pt < 2; ++pt)
#pragma unroll
            for (int ph = 0; ph < 2; ++ph) {
                const float4 lo = Cv[pt][ph][0];  // even w
                const float4 hv = Cv[pt][ph][1];  // odd  w
                const float4 o0 = make_float4(lo.x, hv.x, lo.y, hv.y);
                const float4 o1 = make_float4(lo.z, hv.z, lo.w, hv.w);
                float* p = out + outBase + (long)pt * HO * WO + (long)ph * WO;
                *reinterpret_cast<float4*>(p)     = o0;
                *reinterpret_cast<float4*>(p + 4) = o1;
            }
    }
}

extern "C" void kernel_launch(void* const* d_in, const int* in_sizes, int n_in,
                              void* d_out, int out_size, void* d_ws, size_t ws_size,
                              hipStream_t stream) {
    const float* in = (const float*)d_in[0];
    float* out = (float*)d_out;

    // threads = B*G*T*(H/2)*(W/4) = 2*16*8*64*32 = 524,288
    constexpr int kThreads = 2 * 16 * 8 * 64 * 32;
    constexpr int kBlock = 256;
    ihaar3d_kernel<<<kThreads / kBlock, kBlock, 0, stream>>>(in, out);
}

// Round 8
// 225.775 us; speedup vs baseline: 1.0406x; 1.0406x over previous
//
#include <hip/hip_runtime.h>

// Inverse 3D Haar (UnPatcher): in  [B=2, 8*G=128, T=8,  H=128, W=128] f32
//                              out [B=2,   G=16, 2T=16, 2H=256, 2W=256] f32
//
// out[b,g,2ti+pT,2hi+pH,2wi+pW] = (1/8) * sum_s (-1)^(bits(s)·(pT,pH,pW)) *
//                                 in[b, s*16+g, ti, hi, wi],  s = 4tb+2hb+wb.
//
// R4: nt STORES -> 1.7x write amplification (no L2 write-combine). reverted.
// R5: ideal traffic (131MB W / 65MB F) but 86us vs 43us copy roofline.
// R6: lane-contiguous stores: 84us — store shape not the limiter.
// R7: 4x MLP/thread: 84us at HALF the occupancy — wave-side axes all
//     exonerated; limiter is shared (fabric/HBM + harness restore backlog:
//     256MB of dirty L3 from d_in restore + d_out poison drains during our
//     window; FETCH=65MB=half input proves L3 was thrashed by poison).
// R8 (this): nt LOADS — input is read-once; don't allocate it in L2/L3,
//     cutting in-kernel eviction pressure (each allocation forces a dirty
//     writeback). Loads fully consume each 64B line per instruction, so nt
//     has no coalescing downside (unlike stores).

typedef float f32x2 __attribute__((ext_vector_type(2)));

__device__ __forceinline__ float2 add2(float2 a, float2 b) {
    return make_float2(a.x + b.x, a.y + b.y);
}
__device__ __forceinline__ float2 sub2(float2 a, float2 b) {
    return make_float2(a.x - b.x, a.y - b.y);
}
__device__ __forceinline__ float2 scl2(float2 a, float s) {
    return make_float2(a.x * s, a.y * s);
}

__global__ __launch_bounds__(256) void ihaar3d_kernel(const float* __restrict__ in,
                                                      float* __restrict__ out) {
    constexpr int TI = 8, HI = 128, WI = 128;   // input spatial dims
    constexpr int G  = 16;                      // output channels per batch
    constexpr int WP = WI / 2;                  // 64 float2 per input W-row

    int idx = blockIdx.x * blockDim.x + threadIdx.x;
    const int wp = idx & (WP - 1); idx >>= 6;   // float2 index along W_in
    const int hi = idx & (HI - 1); idx >>= 7;
    const int ti = idx & (TI - 1); idx >>= 3;
    const int g  = idx & (G  - 1); idx >>= 4;
    const int b  = idx;                         // 0..1

    // ---- gather the 8 subband float2s (8B/lane, coalesced, NONTEMPORAL) ----
    const long inBase =
        (((long)(b * 128 + g) * TI + ti) * HI + hi) * WI + (long)wp * 2;
    const long sstride = (long)16 * TI * HI * WI;  // 16 channels * spatial

    float2 v[8];
#pragma unroll
    for (int s = 0; s < 8; ++s) {
        const f32x2 t = __builtin_nontemporal_load(
            reinterpret_cast<const f32x2*>(in + inBase + (long)s * sstride));
        v[s] = make_float2(t.x, t.y);
    }

    // ---- 3-stage butterfly on float2 (two consecutive wi), static idx ----
    float2 A[2][2][2];  // [tb][hb][pW]
#pragma unroll
    for (int tb = 0; tb < 2; ++tb)
#pragma unroll
        for (int hb = 0; hb < 2; ++hb) {
            const float2 lo = v[4 * tb + 2 * hb + 0];
            const float2 hv = v[4 * tb + 2 * hb + 1];
            A[tb][hb][0] = add2(lo, hv);
            A[tb][hb][1] = sub2(lo, hv);
        }
    float2 Bv[2][2][2];  // [tb][pH][pW]
#pragma unroll
    for (int tb = 0; tb < 2; ++tb)
#pragma unroll
        for (int pw = 0; pw < 2; ++pw) {
            Bv[tb][0][pw] = add2(A[tb][0][pw], A[tb][1][pw]);
            Bv[tb][1][pw] = sub2(A[tb][0][pw], A[tb][1][pw]);
        }
    float2 Cv[2][2][2];  // [pT][pH][pW], scaled by 1/8
#pragma unroll
    for (int ph = 0; ph < 2; ++ph)
#pragma unroll
        for (int pw = 0; pw < 2; ++pw) {
            Cv[0][ph][pw] = scl2(add2(Bv[0][ph][pw], Bv[1][ph][pw]), 0.125f);
            Cv[1][ph][pw] = scl2(sub2(Bv[0][ph][pw], Bv[1][ph][pw]), 0.125f);
        }

    // ---- scatter: 4 fully lane-contiguous float4 stores (cached) ----
    const int TO = 2 * TI, HO = 2 * HI, WO = 2 * WI;
    const long outBase =
        (((long)(b * G + g) * TO + 2 * ti) * HO + 2 * hi) * WO + (long)wp * 4;

#pragma unroll
    for (int pt = 0; pt < 2; ++pt)
#pragma unroll
        for (int ph = 0; ph < 2; ++ph) {
            const float2 E = Cv[pt][ph][0];  // even-w outputs at (wi0, wi1)
            const float2 O = Cv[pt][ph][1];  // odd-w  outputs at (wi0, wi1)
            float* p = out + outBase + (long)pt * HO * WO + (long)ph * WO;
            *reinterpret_cast<float4*>(p) = make_float4(E.x, O.x, E.y, O.y);
        }
}

extern "C" void kernel_launch(void* const* d_in, const int* in_sizes, int n_in,
                              void* d_out, int out_size, void* d_ws, size_t ws_size,
                              hipStream_t stream) {
    const float* in = (const float*)d_in[0];
    float* out = (float*)d_out;

    // threads = B*G*T*H*(W/2) = 2*16*8*128*64 = 2,097,152
    constexpr int kThreads = 2 * 16 * 8 * 128 * 64;
    constexpr int kBlock = 256;
    ihaar3d_kernel<<<kThreads / kBlock, kBlock, 0, stream>>>(in, out);
}